// Round 1
// 509.469 us; speedup vs baseline: 1.0079x; 1.0079x over previous
//
#include <hip/hip_runtime.h>

typedef __bf16 bf16x8 __attribute__((ext_vector_type(8)));
typedef float  f32x4  __attribute__((ext_vector_type(4)));

#define B_   32
#define OC   256
#define IC   256
#define HW   3136      // 56*56
#define HP   60        // padded rows (2 extra for n-tail overread)
#define WP   58
#define KTOT 2304      // 9 * 256
#define NT   36        // K-tiles of 64 (9 taps x 4 subtiles)
#define XPAD_BYTES ((size_t)B_ * HP * WP * IC * 2)   // 57,016,320

__device__ __forceinline__ void async16(const void* g, void* l) {
    __builtin_amdgcn_global_load_lds(
        (__attribute__((address_space(1))) void*)g,
        (__attribute__((address_space(3))) void*)l, 16, 0, 0);
}

// ---------------- pass 0: zero the padded border of Xpad ----------------
__global__ __launch_bounds__(256) void zero_border(__bf16* __restrict__ Xpad) {
    int t   = blockIdx.x * 256 + threadIdx.x;
    int b   = t / 11008;
    int r2  = t - b * 11008;
    int pos = r2 >> 5, iq = r2 & 31;
    int r, c;
    if (pos < 232) { int rr = pos / 58; c = pos - rr * 58; r = (rr == 0) ? 0 : (56 + rr); }
    else           { int p2 = pos - 232; r = 1 + (p2 >> 1); c = (p2 & 1) * 57; }
    uint4 z = make_uint4(0u, 0u, 0u, 0u);
    *(uint4*)(Xpad + ((size_t)b * (HP * WP) + r * WP + c) * IC + iq * 8) = z;
}

// ---------------- pass 1: NCHW fp32 -> padded NHWC bf16 ----------------
__global__ __launch_bounds__(256) void transpose_pad(
    const float* __restrict__ X, __bf16* __restrict__ Xpad) {
    int sc = blockIdx.x, icc = blockIdx.y, b = blockIdx.z;
    __shared__ float lt[64][65];
    int tid = threadIdx.x;
    {
        int ci = tid >> 2, sq = tid & 3;
        const float* src = X + (size_t)(b * IC + icc * 64 + ci) * HW + sc * 64 + sq * 16;
        float4 v0 = ((const float4*)src)[0];
        float4 v1 = ((const float4*)src)[1];
        float4 v2 = ((const float4*)src)[2];
        float4 v3 = ((const float4*)src)[3];
        float* dst = &lt[ci][sq * 16];
        ((float4*)dst)[0] = v0; ((float4*)dst)[1] = v1;
        ((float4*)dst)[2] = v2; ((float4*)dst)[3] = v3;
    }
    __syncthreads();
    {
        int p = tid >> 2, iq = tid & 3;
        int s = sc * 64 + p;
        int h = s / 56, w = s - h * 56;
        __bf16* dst = Xpad + ((size_t)b * (HP * WP) + (h + 1) * WP + (w + 1)) * IC + icc * 64 + iq * 16;
        bf16x8 v0, v1;
        #pragma unroll
        for (int j = 0; j < 8; ++j) v0[j] = (__bf16)lt[iq * 16 + j][p];
        #pragma unroll
        for (int j = 0; j < 8; ++j) v1[j] = (__bf16)lt[iq * 16 + 8 + j][p];
        *(bf16x8*)dst = v0;
        *(bf16x8*)(dst + 8) = v1;
    }
}

// ---------------- pass 2: weight synthesis -> Asyn[b][oc][tap*256+ic] bf16 ----------------
__global__ __launch_bounds__(256) void synth(
    const float* __restrict__ se, const float* __restrict__ weight,
    __bf16* __restrict__ Asyn) {
    int oc = blockIdx.x / 9, tap = blockIdx.x - oc * 9;
    int tid = threadIdx.x;
    const float* wrow = weight + ((size_t)(oc * 256 + tid) * 9 + tap) * 64;
    float4 w[16];
    #pragma unroll
    for (int i = 0; i < 16; ++i) w[i] = ((const float4*)wrow)[i];
    size_t outb = (size_t)oc * KTOT + tap * 256 + tid;
    #pragma unroll
    for (int b = 0; b < 32; ++b) {
        const float4* sb = (const float4*)(se + b * 64);  // uniform -> s_load
        float acc = 0.f;
        #pragma unroll
        for (int i = 0; i < 16; ++i) {
            float4 s4 = sb[i];
            acc += w[i].x * s4.x + w[i].y * s4.y + w[i].z * s4.z + w[i].w * s4.w;
        }
        Asyn[(size_t)b * OC * KTOT + outb] = (__bf16)acc;
    }
}

// ---------------- pass 3: per-sample implicit GEMM, 256x256 tile, 8 waves ----------------
// Double-buffered LDS (128 KB), counted vmcnt(8) (never drained in main loop),
// raw s_barrier (no vmcnt drain), setprio around MFMA clusters.
// LDS row = 128 B (64 bf16 k). XOR swizzle: granule g of row r stored at g^(r&7).
// K-chain: 36 tiles of 64 (tap-major: tap = t>>2, sub = t&3).
__global__ __launch_bounds__(512, 2) void conv_mfma(
    const __bf16* __restrict__ Asyn, const __bf16* __restrict__ Xpad,
    const float* __restrict__ bias, float* __restrict__ Out) {
    const int i = blockIdx.x;
    const int xcd = i & 7, slot = i >> 3;        // slot 0..51
    const int bg = slot / 13, ntile = slot - bg * 13;
    const int b = xcd + 8 * bg;                  // all 13 tiles of a sample on one XCD

    __shared__ __bf16 Al[2][256 * 64];           // 2 x 32 KB
    __shared__ __bf16 Bl[2][256 * 64];           // 2 x 32 KB

    const int tid = threadIdx.x;
    const int wid = tid >> 6, lane = tid & 63;   // 8 waves

    // ---- staging: wave wid stages rows [wid*32, wid*32+32) of A and B as 4
    //      chunks of 8 rows; one async16 covers 8 rows x 128 B. lane -> row
    //      lane>>3, physical granule lane&7, logical granule q = (lane&7)^(lane>>3).
    const int rsub = lane >> 3;
    const int q = (lane & 7) ^ rsub;
    const int rowA0 = wid * 32 + rsub;
    const __bf16* aptr = Asyn + (size_t)(b * OC + rowA0) * KTOT + q * 8;
    const __bf16* xb = Xpad + (size_t)b * (HP * WP) * IC;
    const __bf16* bptr[4];
    #pragma unroll
    for (int c = 0; c < 4; ++c) {
        int nn = ntile * 256 + wid * 32 + c * 8 + rsub;
        if (nn >= HW) nn -= HW;                  // tail clamp: valid memory, values discarded
        const int h = nn / 56, w = nn - h * 56;
        bptr[c] = xb + (h * WP + w) * IC + q * 8;
    }

    // ---- fragment read offsets (bytes). Row r granule g at r*128 + (g^(r&7))*16.
    //      Linear in mi/ni since the XOR involves only fr&7. k-half tt -> byte ^64.
    const int wm = wid >> 2;                     // M half (0..1)
    const int wn = wid & 3;                      // N quarter (0..3)
    const int fr = lane & 15, fq = lane >> 4;
    const int swz = (fq ^ (fr & 7)) * 16;
    const int abase = (wm * 128 + fr) * 128 + swz;   // + mi*2048
    const int bbase = (wn * 64 + fr) * 128 + swz;    // + ni*2048

    f32x4 acc[8][4] = {};

    auto STAGE = [&](int t, int s) {
        const int tap = t >> 2, sub = t & 3;
        const int kh = (tap * 11) >> 5;          // tap/3 for tap<=8
        const int kw = tap - kh * 3;
        const int aoK = t * 64;                  // Asyn K is linear: tap*256+sub*64
        const int boK = (kh * WP + kw) * IC + sub * 64;
        char* al = (char*)&Al[s][0] + wid * 4096;
        char* bl = (char*)&Bl[s][0] + wid * 4096;
        #pragma unroll
        for (int c = 0; c < 4; ++c)
            async16(aptr + (size_t)c * (8 * KTOT) + aoK, al + c * 1024);
        #pragma unroll
        for (int c = 0; c < 4; ++c)
            async16(bptr[c] + boK, bl + c * 1024);
    };

    auto COMPUTE = [&](int s) {
        const char* Ab = (const char*)&Al[s][0];
        const char* Bb = (const char*)&Bl[s][0];
        bf16x8 bv[4][2];
        #pragma unroll
        for (int ni = 0; ni < 4; ++ni)
            #pragma unroll
            for (int tt = 0; tt < 2; ++tt)
                bv[ni][tt] = *(const bf16x8*)(Bb + ((bbase + ni * 2048) ^ (tt * 64)));
        #pragma unroll
        for (int p = 0; p < 4; ++p) {            // quadrant: m-frags {2p, 2p+1}
            bf16x8 af[2][2];
            #pragma unroll
            for (int m2 = 0; m2 < 2; ++m2)
                #pragma unroll
                for (int tt = 0; tt < 2; ++tt)
                    af[m2][tt] = *(const bf16x8*)(Ab + ((abase + (2 * p + m2) * 2048) ^ (tt * 64)));
            __builtin_amdgcn_s_setprio(1);
            #pragma unroll
            for (int m2 = 0; m2 < 2; ++m2)
                #pragma unroll
                for (int ni = 0; ni < 4; ++ni) {
                    acc[2 * p + m2][ni] = __builtin_amdgcn_mfma_f32_16x16x32_bf16(
                        af[m2][0], bv[ni][0], acc[2 * p + m2][ni], 0, 0, 0);
                    acc[2 * p + m2][ni] = __builtin_amdgcn_mfma_f32_16x16x32_bf16(
                        af[m2][1], bv[ni][1], acc[2 * p + m2][ni], 0, 0, 0);
                }
            __builtin_amdgcn_s_setprio(0);
        }
    };

    STAGE(0, 0);                                 // prologue fill
    #pragma unroll 2
    for (int t = 0; t < NT; ++t) {
        if (t + 1 < NT) {
            STAGE(t + 1, (t + 1) & 1);           // next tile into the other buffer
            asm volatile("s_waitcnt vmcnt(8)" ::: "memory");   // wait ONLY tile t's loads
        } else {
            asm volatile("s_waitcnt vmcnt(0)" ::: "memory");
        }
        __builtin_amdgcn_s_barrier();            // all waves' tile-t loads landed
        asm volatile("" ::: "memory");
        COMPUTE(t & 1);
        asm volatile("" ::: "memory");           // reads retired (lgkm waited before MFMAs)
        __builtin_amdgcn_s_barrier();            // protect buf before next overwrite
        asm volatile("" ::: "memory");
    }

    // ---- store: D row = fq*4 + reg, col = fr ----
    #pragma unroll
    for (int mi = 0; mi < 8; ++mi) {
        #pragma unroll
        for (int r = 0; r < 4; ++r) {
            const int row = wm * 128 + mi * 16 + fq * 4 + r;
            const float bvv = bias[row];
            float* orow = Out + (size_t)(b * OC + row) * HW;
            #pragma unroll
            for (int ni = 0; ni < 4; ++ni) {
                const int col = ntile * 256 + wn * 64 + ni * 16 + fr;
                if (col < HW) orow[col] = acc[mi][ni][r] + bvv;
            }
        }
    }
}

extern "C" void kernel_launch(void* const* d_in, const int* in_sizes, int n_in,
                              void* d_out, int out_size, void* d_ws, size_t ws_size,
                              hipStream_t stream) {
    const float* X    = (const float*)d_in[0];   // [32,256,56,56]
    const float* se   = (const float*)d_in[1];   // [32,64]
    const float* Wt   = (const float*)d_in[2];   // [589824,64]
    const float* bias = (const float*)d_in[3];   // [256]
    __bf16* Xpad = (__bf16*)d_ws;                           // 57.0 MB
    __bf16* Asyn = (__bf16*)((char*)d_ws + XPAD_BYTES);     // 37.75 MB
    float*  Out  = (float*)d_out;

    zero_border<<<1376, 256, 0, stream>>>(Xpad);
    transpose_pad<<<dim3(49, 4, 32), 256, 0, stream>>>(X, Xpad);
    synth<<<2304, 256, 0, stream>>>(se, Wt, Asyn);
    conv_mfma<<<416, 512, 0, stream>>>(Asyn, Xpad, bias, Out);
}

// Round 2
// 489.530 us; speedup vs baseline: 1.0490x; 1.0407x over previous
//
#include <hip/hip_runtime.h>

typedef __bf16 bf16x8 __attribute__((ext_vector_type(8)));
typedef float  f32x4  __attribute__((ext_vector_type(4)));

#define B_   32
#define OC   256
#define IC   256
#define HW   3136      // 56*56
#define HP   60        // padded rows (2 extra for n-tail overread)
#define WP   58
#define KTOT 2304      // 9 * 256
#define NT   36        // K-tiles of 64 (9 taps x 4 subtiles)
#define XPAD_BYTES ((size_t)B_ * HP * WP * IC * 2)   // 57,016,320

__device__ __forceinline__ void async16(const void* g, void* l) {
    __builtin_amdgcn_global_load_lds(
        (__attribute__((address_space(1))) void*)g,
        (__attribute__((address_space(3))) void*)l, 16, 0, 0);
}

// ---------------- pass 0: zero the padded border of Xpad ----------------
__global__ __launch_bounds__(256) void zero_border(__bf16* __restrict__ Xpad) {
    int t   = blockIdx.x * 256 + threadIdx.x;
    int b   = t / 11008;
    int r2  = t - b * 11008;
    int pos = r2 >> 5, iq = r2 & 31;
    int r, c;
    if (pos < 232) { int rr = pos / 58; c = pos - rr * 58; r = (rr == 0) ? 0 : (56 + rr); }
    else           { int p2 = pos - 232; r = 1 + (p2 >> 1); c = (p2 & 1) * 57; }
    uint4 z = make_uint4(0u, 0u, 0u, 0u);
    *(uint4*)(Xpad + ((size_t)b * (HP * WP) + r * WP + c) * IC + iq * 8) = z;
}

// ---------------- pass 1: NCHW fp32 -> padded NHWC bf16 ----------------
__global__ __launch_bounds__(256) void transpose_pad(
    const float* __restrict__ X, __bf16* __restrict__ Xpad) {
    int sc = blockIdx.x, icc = blockIdx.y, b = blockIdx.z;
    __shared__ float lt[64][65];
    int tid = threadIdx.x;
    {
        int ci = tid >> 2, sq = tid & 3;
        const float* src = X + (size_t)(b * IC + icc * 64 + ci) * HW + sc * 64 + sq * 16;
        float4 v0 = ((const float4*)src)[0];
        float4 v1 = ((const float4*)src)[1];
        float4 v2 = ((const float4*)src)[2];
        float4 v3 = ((const float4*)src)[3];
        float* dst = &lt[ci][sq * 16];
        ((float4*)dst)[0] = v0; ((float4*)dst)[1] = v1;
        ((float4*)dst)[2] = v2; ((float4*)dst)[3] = v3;
    }
    __syncthreads();
    {
        int p = tid >> 2, iq = tid & 3;
        int s = sc * 64 + p;
        int h = s / 56, w = s - h * 56;
        __bf16* dst = Xpad + ((size_t)b * (HP * WP) + (h + 1) * WP + (w + 1)) * IC + icc * 64 + iq * 16;
        bf16x8 v0, v1;
        #pragma unroll
        for (int j = 0; j < 8; ++j) v0[j] = (__bf16)lt[iq * 16 + j][p];
        #pragma unroll
        for (int j = 0; j < 8; ++j) v1[j] = (__bf16)lt[iq * 16 + 8 + j][p];
        *(bf16x8*)dst = v0;
        *(bf16x8*)(dst + 8) = v1;
    }
}

// ---------------- pass 2: weight synthesis -> Asyn[b][oc][tap*256+ic] bf16 ----------------
__global__ __launch_bounds__(256) void synth(
    const float* __restrict__ se, const float* __restrict__ weight,
    __bf16* __restrict__ Asyn) {
    int oc = blockIdx.x / 9, tap = blockIdx.x - oc * 9;
    int tid = threadIdx.x;
    const float* wrow = weight + ((size_t)(oc * 256 + tid) * 9 + tap) * 64;
    float4 w[16];
    #pragma unroll
    for (int i = 0; i < 16; ++i) w[i] = ((const float4*)wrow)[i];
    size_t outb = (size_t)oc * KTOT + tap * 256 + tid;
    #pragma unroll
    for (int b = 0; b < 32; ++b) {
        const float4* sb = (const float4*)(se + b * 64);  // uniform -> s_load
        float acc = 0.f;
        #pragma unroll
        for (int i = 0; i < 16; ++i) {
            float4 s4 = sb[i];
            acc += w[i].x * s4.x + w[i].y * s4.y + w[i].z * s4.z + w[i].w * s4.w;
        }
        Asyn[(size_t)b * OC * KTOT + outb] = (__bf16)acc;
    }
}

// ---------------- pass 3: per-sample implicit GEMM, 256x256 tile, 8 waves ----------------
// m201-style 8-phase schedule: per K-tile, 4 quadrant-phases of
// {ds_read frags | stage ONE half-tile | s_barrier | lgkmcnt(0) | 16 MFMA | s_barrier}.
// Stagger: A0(t+1)@P0, A1(t+1)@P1, B0(t+2)@P2, B1(t+2)@P3; vmcnt(4) once per tile
// (at P3) -- never drained to 0 in steady state. Peak 12 loads in flight.
// LDS row = 128 B (64 bf16 k). XOR swizzle: granule g of row r stored at g^(r&7).
__global__ __launch_bounds__(512, 2) void conv_mfma(
    const __bf16* __restrict__ Asyn, const __bf16* __restrict__ Xpad,
    const float* __restrict__ bias, float* __restrict__ Out) {
    const int i = blockIdx.x;
    const int xcd = i & 7, slot = i >> 3;        // slot 0..51
    const int bg = slot / 13, ntile = slot - bg * 13;
    const int b = xcd + 8 * bg;                  // all 13 tiles of a sample on one XCD

    __shared__ __bf16 Al[2][256 * 64];           // 2 x 32 KB
    __shared__ __bf16 Bl[2][256 * 64];           // 2 x 32 KB

    const int tid = threadIdx.x;
    const int wid = tid >> 6, lane = tid & 63;   // 8 waves

    // ---- staging map (block-wide per half-tile: 128 rows, 2 async16/thread).
    //      lane -> row lane>>3, physical granule lane&7, logical q = (lane&7)^(lane>>3).
    const int rsub = lane >> 3;
    const int q = (lane & 7) ^ rsub;
    const __bf16* aptr[2][2];                    // [half][chunk] rows 128h + wid*16 + c*8 + rsub
    const __bf16* bptr[2][2];
    const __bf16* xb = Xpad + (size_t)b * (HP * WP) * IC;
    #pragma unroll
    for (int h = 0; h < 2; ++h)
        #pragma unroll
        for (int c = 0; c < 2; ++c) {
            const int r = h * 128 + wid * 16 + c * 8 + rsub;
            aptr[h][c] = Asyn + (size_t)(b * OC + r) * KTOT + q * 8;
            int nn = ntile * 256 + r;            // may exceed 3135
            if (nn >= HW) nn -= HW;              // tail clamp: valid memory, values discarded
            const int hh = nn / 56, ww = nn - hh * 56;
            bptr[h][c] = xb + (hh * WP + ww) * IC + q * 8;
        }

    // ---- fragment read offsets (bytes). Row r granule g at r*128 + (g^(r&7))*16.
    //      Linear in mi/ni since the XOR involves only fr&7. k-half tt -> byte ^64.
    const int wm = wid >> 2;                     // M half (0..1)
    const int wn = wid & 3;                      // N quarter (0..3)
    const int fr = lane & 15, fq = lane >> 4;
    const int swz = (fq ^ (fr & 7)) * 16;
    const int abase = (wm * 128 + fr) * 128 + swz;   // + mi*2048
    const int bbase = (wn * 64 + fr) * 128 + swz;    // + ni*2048

    f32x4 acc[8][4] = {};

    auto STAGE_A = [&](int t, int cur, int h) {  // tile t's A-half h -> buf cur
        char* base = (char*)&Al[cur][0] + (h * 128 + wid * 16) * 128;
        const int ko = t * 64;                   // Asyn K is linear: t*64
        async16(aptr[h][0] + ko, base);
        async16(aptr[h][1] + ko, base + 1024);
    };
    auto STAGE_B = [&](int t, int cur, int h) {
        const int tap = t >> 2, sub = t & 3;
        const int kh = tap / 3, kw = tap - kh * 3;
        const int ko = (kh * WP + kw) * IC + sub * 64;
        char* base = (char*)&Bl[cur][0] + (h * 128 + wid * 16) * 128;
        async16(bptr[h][0] + ko, base);
        async16(bptr[h][1] + ko, base + 1024);
    };

    auto TILE = [&](int t, int cur) {
        const char* Ab = (const char*)&Al[cur][0];
        const char* Bb = (const char*)&Bl[cur][0];
        bf16x8 bv[4][2];
        #pragma unroll
        for (int qq = 0; qq < 4; ++qq) {
            // -- phase qq: ds_read frags for THIS phase's quadrant
            if (qq == 0) {
                #pragma unroll
                for (int ni = 0; ni < 4; ++ni)
                    #pragma unroll
                    for (int tt = 0; tt < 2; ++tt)
                        bv[ni][tt] = *(const bf16x8*)(Bb + ((bbase + ni * 2048) ^ (tt * 64)));
            }
            bf16x8 af[2][2];
            #pragma unroll
            for (int m2 = 0; m2 < 2; ++m2)
                #pragma unroll
                for (int tt = 0; tt < 2; ++tt)
                    af[m2][tt] = *(const bf16x8*)(Ab + ((abase + (2 * qq + m2) * 2048) ^ (tt * 64)));
            // -- stage exactly one half-tile (staggered; regions dead >=2 barriers)
            if (qq == 0 && t + 1 < NT) STAGE_A(t + 1, cur ^ 1, 0);
            if (qq == 1 && t + 1 < NT) STAGE_A(t + 1, cur ^ 1, 1);
            if (qq == 2 && t + 2 < NT) STAGE_B(t + 2, cur, 0);
            if (qq == 3) {
                if (t + 2 < NT) STAGE_B(t + 2, cur, 1);
                // boundary wait: A(t+1)+B(t+1) landed; only B(t+2) (4 loads) may fly
                if (t < NT - 2) asm volatile("s_waitcnt vmcnt(4)" ::: "memory");
                else            asm volatile("s_waitcnt vmcnt(0)" ::: "memory");
            }
            if (qq == 0) asm volatile("s_waitcnt lgkmcnt(8)" ::: "memory");
            __builtin_amdgcn_s_barrier();
            asm volatile("s_waitcnt lgkmcnt(0)" ::: "memory");
            __builtin_amdgcn_sched_barrier(0);
            __builtin_amdgcn_s_setprio(1);
            #pragma unroll
            for (int m2 = 0; m2 < 2; ++m2)
                #pragma unroll
                for (int ni = 0; ni < 4; ++ni) {
                    acc[2 * qq + m2][ni] = __builtin_amdgcn_mfma_f32_16x16x32_bf16(
                        af[m2][0], bv[ni][0], acc[2 * qq + m2][ni], 0, 0, 0);
                    acc[2 * qq + m2][ni] = __builtin_amdgcn_mfma_f32_16x16x32_bf16(
                        af[m2][1], bv[ni][1], acc[2 * qq + m2][ni], 0, 0, 0);
                }
            __builtin_amdgcn_s_setprio(0);
            __builtin_amdgcn_s_barrier();
        }
    };

    // prologue: A(0), B(0), B(1); allow B(1) to stay in flight
    STAGE_A(0, 0, 0); STAGE_A(0, 0, 1);
    STAGE_B(0, 0, 0); STAGE_B(0, 0, 1);
    STAGE_B(1, 1, 0); STAGE_B(1, 1, 1);
    asm volatile("s_waitcnt vmcnt(4)" ::: "memory");
    __builtin_amdgcn_s_barrier();

    #pragma unroll 1
    for (int t2 = 0; t2 < NT; t2 += 2) {
        TILE(t2, 0);
        TILE(t2 + 1, 1);
    }

    // ---- store: D row = fq*4 + reg, col = fr ----
    #pragma unroll
    for (int mi = 0; mi < 8; ++mi) {
        #pragma unroll
        for (int r = 0; r < 4; ++r) {
            const int row = wm * 128 + mi * 16 + fq * 4 + r;
            const float bvv = bias[row];
            float* orow = Out + (size_t)(b * OC + row) * HW;
            #pragma unroll
            for (int ni = 0; ni < 4; ++ni) {
                const int col = ntile * 256 + wn * 64 + ni * 16 + fr;
                if (col < HW) orow[col] = acc[mi][ni][r] + bvv;
            }
        }
    }
}

extern "C" void kernel_launch(void* const* d_in, const int* in_sizes, int n_in,
                              void* d_out, int out_size, void* d_ws, size_t ws_size,
                              hipStream_t stream) {
    const float* X    = (const float*)d_in[0];   // [32,256,56,56]
    const float* se   = (const float*)d_in[1];   // [32,64]
    const float* Wt   = (const float*)d_in[2];   // [589824,64]
    const float* bias = (const float*)d_in[3];   // [256]
    __bf16* Xpad = (__bf16*)d_ws;                           // 57.0 MB
    __bf16* Asyn = (__bf16*)((char*)d_ws + XPAD_BYTES);     // 37.75 MB
    float*  Out  = (float*)d_out;

    zero_border<<<1376, 256, 0, stream>>>(Xpad);
    transpose_pad<<<dim3(49, 4, 32), 256, 0, stream>>>(X, Xpad);
    synth<<<2304, 256, 0, stream>>>(se, Wt, Asyn);
    conv_mfma<<<416, 512, 0, stream>>>(Asyn, Xpad, bias, Out);
}

// Round 3
// 476.367 us; speedup vs baseline: 1.0779x; 1.0276x over previous
//
#include <hip/hip_runtime.h>

typedef __bf16 bf16x8 __attribute__((ext_vector_type(8)));
typedef float  f32x4  __attribute__((ext_vector_type(4)));

#define B_   32
#define OC   256
#define IC   256
#define HW   3136      // 56*56
#define HP   60        // padded rows (2 extra for n-tail overread)
#define WP   58
#define KTOT 2304      // 9 * 256
#define NT   36        // K-tiles of 64 (9 taps x 4 subtiles)
#define NTILE 224      // N per block: 14 * 224 = 3136 exact cover
#define XPAD_BYTES ((size_t)B_ * HP * WP * IC * 2)   // 57,016,320

__device__ __forceinline__ void async16(const void* g, void* l) {
    __builtin_amdgcn_global_load_lds(
        (__attribute__((address_space(1))) void*)g,
        (__attribute__((address_space(3))) void*)l, 16, 0, 0);
}

// ---------------- pass 0: zero the padded border of Xpad ----------------
__global__ __launch_bounds__(256) void zero_border(__bf16* __restrict__ Xpad) {
    int t   = blockIdx.x * 256 + threadIdx.x;
    int b   = t / 11008;
    int r2  = t - b * 11008;
    int pos = r2 >> 5, iq = r2 & 31;
    int r, c;
    if (pos < 232) { int rr = pos / 58; c = pos - rr * 58; r = (rr == 0) ? 0 : (56 + rr); }
    else           { int p2 = pos - 232; r = 1 + (p2 >> 1); c = (p2 & 1) * 57; }
    uint4 z = make_uint4(0u, 0u, 0u, 0u);
    *(uint4*)(Xpad + ((size_t)b * (HP * WP) + r * WP + c) * IC + iq * 8) = z;
}

// ---------------- pass 1: NCHW fp32 -> padded NHWC bf16 ----------------
__global__ __launch_bounds__(256) void transpose_pad(
    const float* __restrict__ X, __bf16* __restrict__ Xpad) {
    int sc = blockIdx.x, icc = blockIdx.y, b = blockIdx.z;
    __shared__ float lt[64][65];
    int tid = threadIdx.x;
    {
        int ci = tid >> 2, sq = tid & 3;
        const float* src = X + (size_t)(b * IC + icc * 64 + ci) * HW + sc * 64 + sq * 16;
        float4 v0 = ((const float4*)src)[0];
        float4 v1 = ((const float4*)src)[1];
        float4 v2 = ((const float4*)src)[2];
        float4 v3 = ((const float4*)src)[3];
        float* dst = &lt[ci][sq * 16];
        ((float4*)dst)[0] = v0; ((float4*)dst)[1] = v1;
        ((float4*)dst)[2] = v2; ((float4*)dst)[3] = v3;
    }
    __syncthreads();
    {
        int p = tid >> 2, iq = tid & 3;
        int s = sc * 64 + p;
        int h = s / 56, w = s - h * 56;
        __bf16* dst = Xpad + ((size_t)b * (HP * WP) + (h + 1) * WP + (w + 1)) * IC + icc * 64 + iq * 16;
        bf16x8 v0, v1;
        #pragma unroll
        for (int j = 0; j < 8; ++j) v0[j] = (__bf16)lt[iq * 16 + j][p];
        #pragma unroll
        for (int j = 0; j < 8; ++j) v1[j] = (__bf16)lt[iq * 16 + 8 + j][p];
        *(bf16x8*)dst = v0;
        *(bf16x8*)(dst + 8) = v1;
    }
}

// ---------------- pass 2: weight synthesis -> Asyn[b][oc][tap*256+ic] bf16 ----------------
__global__ __launch_bounds__(256) void synth(
    const float* __restrict__ se, const float* __restrict__ weight,
    __bf16* __restrict__ Asyn) {
    int oc = blockIdx.x / 9, tap = blockIdx.x - oc * 9;
    int tid = threadIdx.x;
    const float* wrow = weight + ((size_t)(oc * 256 + tid) * 9 + tap) * 64;
    float4 w[16];
    #pragma unroll
    for (int i = 0; i < 16; ++i) w[i] = ((const float4*)wrow)[i];
    size_t outb = (size_t)oc * KTOT + tap * 256 + tid;
    #pragma unroll
    for (int b = 0; b < 32; ++b) {
        const float4* sb = (const float4*)(se + b * 64);  // uniform -> s_load
        float acc = 0.f;
        #pragma unroll
        for (int i = 0; i < 16; ++i) {
            float4 s4 = sb[i];
            acc += w[i].x * s4.x + w[i].y * s4.y + w[i].z * s4.z + w[i].w * s4.w;
        }
        Asyn[(size_t)b * OC * KTOT + outb] = (__bf16)acc;
    }
}

// ---------------- pass 3: per-sample implicit GEMM, 256x224 tile, 8 waves ----------------
// 4 phases per K-tile: {ds_read frags | stage ONE half-tile | [P3: counted vmcnt]
//  | s_barrier | setprio(1) MFMA setprio(0) | s_barrier}. NO lgkmcnt pinning, NO
// sched_barrier: compiler emits fine-grained lgkmcnt for its own ds_read->MFMA deps.
// Stagger: A(t+1)@P0/P1 (other buf), B(t+2)@P2/P3 (same buf, dead rows); vmcnt(4)
// once per tile -- 4 loads (B t+2) always in flight in steady state.
// Waves 4M x 2N: per-wave 64x112 (phase q = m-frag q, 7 n-frags x 2 k-halves).
// N covered exactly: 14 tiles x 224 = 3136 (B staged 256 rows, rows 224+ dead).
// LDS row = 128 B (64 bf16 k). XOR swizzle: granule g of row r stored at g^(r&7).
__global__ __launch_bounds__(512, 2) void conv_mfma(
    const __bf16* __restrict__ Asyn, const __bf16* __restrict__ Xpad,
    const float* __restrict__ bias, float* __restrict__ Out) {
    const int i = blockIdx.x;
    const int xcd = i & 7, slot = i >> 3;        // slot 0..55
    const int bg = slot / 14, ntile = slot - bg * 14;
    const int b = xcd + 8 * bg;                  // all 14 tiles of a sample on one XCD

    __shared__ __bf16 Al[2][256 * 64];           // 2 x 32 KB
    __shared__ __bf16 Bl[2][256 * 64];           // 2 x 32 KB

    const int tid = threadIdx.x;
    const int wid = tid >> 6, lane = tid & 63;   // 8 waves

    // ---- staging map (block-wide per half-tile: 128 rows, 2 async16/thread).
    //      lane -> row lane>>3, physical granule lane&7, logical q = (lane&7)^(lane>>3).
    const int rsub = lane >> 3;
    const int q = (lane & 7) ^ rsub;
    const __bf16* aptr[2][2];                    // [half][chunk] rows 128h + wid*16 + c*8 + rsub
    const __bf16* bptr[2][2];
    const __bf16* xb = Xpad + (size_t)b * (HP * WP) * IC;
    #pragma unroll
    for (int h = 0; h < 2; ++h)
        #pragma unroll
        for (int c = 0; c < 2; ++c) {
            const int r = h * 128 + wid * 16 + c * 8 + rsub;
            aptr[h][c] = Asyn + (size_t)(b * OC + r) * KTOT + q * 8;
            int nn = ntile * NTILE + r;          // rows 224..255 staged but never consumed
            if (nn >= HW) nn -= HW;              // tail clamp: valid memory, values discarded
            const int hh = nn / 56, ww = nn - hh * 56;
            bptr[h][c] = xb + (hh * WP + ww) * IC + q * 8;
        }

    // ---- fragment read offsets (bytes). Row r granule g at r*128 + (g^(r&7))*16.
    //      Linear in frag index since the XOR involves only fr&7. k-half tt -> byte ^64.
    const int wm = wid >> 1;                     // M quarter (0..3), 64 rows
    const int wn = wid & 1;                      // N half (0..1), 112 cols
    const int fr = lane & 15, fq = lane >> 4;
    const int swz = (fq ^ (fr & 7)) * 16;
    const int abase = (wm * 64 + fr) * 128 + swz;    // + mi*2048 (mi = phase 0..3)
    const int bbase = (wn * 112 + fr) * 128 + swz;   // + ni*2048 (ni 0..6)

    f32x4 acc[4][7] = {};

    auto STAGE_A = [&](int t, int cur, int h) {  // tile t's A-half h -> buf cur
        char* base = (char*)&Al[cur][0] + (h * 128 + wid * 16) * 128;
        const int ko = t * 64;                   // Asyn K is linear: t*64
        async16(aptr[h][0] + ko, base);
        async16(aptr[h][1] + ko, base + 1024);
    };
    auto STAGE_B = [&](int t, int cur, int h) {
        const int tap = t >> 2, sub = t & 3;
        const int kh = tap / 3, kw = tap - kh * 3;
        const int ko = (kh * WP + kw) * IC + sub * 64;
        char* base = (char*)&Bl[cur][0] + (h * 128 + wid * 16) * 128;
        async16(bptr[h][0] + ko, base);
        async16(bptr[h][1] + ko, base + 1024);
    };

    auto TILE = [&](int t, int cur) {
        const char* Ab = (const char*)&Al[cur][0];
        const char* Bb = (const char*)&Bl[cur][0];
        bf16x8 bv[7][2];
        #pragma unroll
        for (int qq = 0; qq < 4; ++qq) {
            // -- phase qq: frag reads (B bulk at qq0; A frag for this phase's m-row)
            if (qq == 0) {
                #pragma unroll
                for (int ni = 0; ni < 7; ++ni)
                    #pragma unroll
                    for (int tt = 0; tt < 2; ++tt)
                        bv[ni][tt] = *(const bf16x8*)(Bb + ((bbase + ni * 2048) ^ (tt * 64)));
            }
            bf16x8 af[2];
            #pragma unroll
            for (int tt = 0; tt < 2; ++tt)
                af[tt] = *(const bf16x8*)(Ab + ((abase + qq * 2048) ^ (tt * 64)));
            // -- stage exactly one half-tile (regions dead >=2 barriers, see header)
            if (qq == 0 && t + 1 < NT) STAGE_A(t + 1, cur ^ 1, 0);
            if (qq == 1 && t + 1 < NT) STAGE_A(t + 1, cur ^ 1, 1);
            if (qq == 2 && t + 2 < NT) STAGE_B(t + 2, cur, 0);
            if (qq == 3) {
                if (t + 2 < NT) STAGE_B(t + 2, cur, 1);
                // boundary wait: A(t+1)+B(t+1) landed; only B(t+2) (4 loads) may fly
                if (t < NT - 2) asm volatile("s_waitcnt vmcnt(4)" ::: "memory");
                else            asm volatile("s_waitcnt vmcnt(0)" ::: "memory");
            }
            __builtin_amdgcn_s_barrier();
            __builtin_amdgcn_s_setprio(1);
            #pragma unroll
            for (int tt = 0; tt < 2; ++tt)
                #pragma unroll
                for (int ni = 0; ni < 7; ++ni)
                    acc[qq][ni] = __builtin_amdgcn_mfma_f32_16x16x32_bf16(
                        af[tt], bv[ni][tt], acc[qq][ni], 0, 0, 0);
            __builtin_amdgcn_s_setprio(0);
            __builtin_amdgcn_s_barrier();
        }
    };

    // prologue: A(0), B(0), B(1); allow B(1) to stay in flight
    STAGE_A(0, 0, 0); STAGE_A(0, 0, 1);
    STAGE_B(0, 0, 0); STAGE_B(0, 0, 1);
    STAGE_B(1, 1, 0); STAGE_B(1, 1, 1);
    asm volatile("s_waitcnt vmcnt(4)" ::: "memory");
    __builtin_amdgcn_s_barrier();

    #pragma unroll 1
    for (int t2 = 0; t2 < NT; t2 += 2) {
        TILE(t2, 0);
        TILE(t2 + 1, 1);
    }

    // ---- store: D row = fq*4 + reg, col = fr. Exact cover -> no col guard ----
    #pragma unroll
    for (int mi = 0; mi < 4; ++mi) {
        #pragma unroll
        for (int r = 0; r < 4; ++r) {
            const int row = wm * 64 + mi * 16 + fq * 4 + r;
            const float bvv = bias[row];
            float* orow = Out + (size_t)(b * OC + row) * HW;
            #pragma unroll
            for (int ni = 0; ni < 7; ++ni) {
                const int col = ntile * NTILE + wn * 112 + ni * 16 + fr;
                orow[col] = acc[mi][ni][r] + bvv;
            }
        }
    }
}

extern "C" void kernel_launch(void* const* d_in, const int* in_sizes, int n_in,
                              void* d_out, int out_size, void* d_ws, size_t ws_size,
                              hipStream_t stream) {
    const float* X    = (const float*)d_in[0];   // [32,256,56,56]
    const float* se   = (const float*)d_in[1];   // [32,64]
    const float* Wt   = (const float*)d_in[2];   // [589824,64]
    const float* bias = (const float*)d_in[3];   // [256]
    __bf16* Xpad = (__bf16*)d_ws;                           // 57.0 MB
    __bf16* Asyn = (__bf16*)((char*)d_ws + XPAD_BYTES);     // 37.75 MB
    float*  Out  = (float*)d_out;

    zero_border<<<1376, 256, 0, stream>>>(Xpad);
    transpose_pad<<<dim3(49, 4, 32), 256, 0, stream>>>(X, Xpad);
    synth<<<2304, 256, 0, stream>>>(se, Wt, Asyn);
    conv_mfma<<<448, 512, 0, stream>>>(Asyn, Xpad, bias, Out);
}

// Round 4
// 465.821 us; speedup vs baseline: 1.1023x; 1.0226x over previous
//
#include <hip/hip_runtime.h>

typedef __bf16 bf16x8 __attribute__((ext_vector_type(8)));
typedef float  f32x4  __attribute__((ext_vector_type(4)));

#define B_   32
#define OC   256
#define IC   256
#define HW   3136      // 56*56
#define HP   60        // padded rows (2 extra for n-tail overread)
#define WP   58
#define KTOT 2304      // 9 * 256
#define NT   36        // K-tiles of 64 (9 taps x 4 subtiles)
#define NTILE 224      // N per block: 14 * 224 = 3136 exact cover
#define XPAD_BYTES ((size_t)B_ * HP * WP * IC * 2)   // 57,016,320

__device__ __forceinline__ void async16(const void* g, void* l) {
    __builtin_amdgcn_global_load_lds(
        (__attribute__((address_space(1))) void*)g,
        (__attribute__((address_space(3))) void*)l, 16, 0, 0);
}

// ---------------- pass 0: zero the padded border of Xpad ----------------
__global__ __launch_bounds__(256) void zero_border(__bf16* __restrict__ Xpad) {
    int t   = blockIdx.x * 256 + threadIdx.x;
    int b   = t / 11008;
    int r2  = t - b * 11008;
    int pos = r2 >> 5, iq = r2 & 31;
    int r, c;
    if (pos < 232) { int rr = pos / 58; c = pos - rr * 58; r = (rr == 0) ? 0 : (56 + rr); }
    else           { int p2 = pos - 232; r = 1 + (p2 >> 1); c = (p2 & 1) * 57; }
    uint4 z = make_uint4(0u, 0u, 0u, 0u);
    *(uint4*)(Xpad + ((size_t)b * (HP * WP) + r * WP + c) * IC + iq * 8) = z;
}

// ---------------- pass 1: NCHW fp32 -> padded NHWC bf16 ----------------
__global__ __launch_bounds__(256) void transpose_pad(
    const float* __restrict__ X, __bf16* __restrict__ Xpad) {
    int sc = blockIdx.x, icc = blockIdx.y, b = blockIdx.z;
    __shared__ float lt[64][65];
    int tid = threadIdx.x;
    {
        int ci = tid >> 2, sq = tid & 3;
        const float* src = X + (size_t)(b * IC + icc * 64 + ci) * HW + sc * 64 + sq * 16;
        float4 v0 = ((const float4*)src)[0];
        float4 v1 = ((const float4*)src)[1];
        float4 v2 = ((const float4*)src)[2];
        float4 v3 = ((const float4*)src)[3];
        float* dst = &lt[ci][sq * 16];
        ((float4*)dst)[0] = v0; ((float4*)dst)[1] = v1;
        ((float4*)dst)[2] = v2; ((float4*)dst)[3] = v3;
    }
    __syncthreads();
    {
        int p = tid >> 2, iq = tid & 3;
        int s = sc * 64 + p;
        int h = s / 56, w = s - h * 56;
        __bf16* dst = Xpad + ((size_t)b * (HP * WP) + (h + 1) * WP + (w + 1)) * IC + icc * 64 + iq * 16;
        bf16x8 v0, v1;
        #pragma unroll
        for (int j = 0; j < 8; ++j) v0[j] = (__bf16)lt[iq * 16 + j][p];
        #pragma unroll
        for (int j = 0; j < 8; ++j) v1[j] = (__bf16)lt[iq * 16 + 8 + j][p];
        *(bf16x8*)dst = v0;
        *(bf16x8*)(dst + 8) = v1;
    }
}

// ---------------- pass 2: weight synthesis -> Asyn[b][oc][tap*256+ic] bf16 ----------------
__global__ __launch_bounds__(256) void synth(
    const float* __restrict__ se, const float* __restrict__ weight,
    __bf16* __restrict__ Asyn) {
    int oc = blockIdx.x / 9, tap = blockIdx.x - oc * 9;
    int tid = threadIdx.x;
    const float* wrow = weight + ((size_t)(oc * 256 + tid) * 9 + tap) * 64;
    float4 w[16];
    #pragma unroll
    for (int i = 0; i < 16; ++i) w[i] = ((const float4*)wrow)[i];
    size_t outb = (size_t)oc * KTOT + tap * 256 + tid;
    #pragma unroll
    for (int b = 0; b < 32; ++b) {
        const float4* sb = (const float4*)(se + b * 64);  // uniform -> s_load
        float acc = 0.f;
        #pragma unroll
        for (int i = 0; i < 16; ++i) {
            float4 s4 = sb[i];
            acc += w[i].x * s4.x + w[i].y * s4.y + w[i].z * s4.z + w[i].w * s4.w;
        }
        Asyn[(size_t)b * OC * KTOT + outb] = (__bf16)acc;
    }
}

// ---------------- pass 3: per-sample implicit GEMM, 256x224 tile, 8 waves ----------------
// 2 phases per K-tile (barrier count halved vs 4-phase):
//   P0: {ALL frag reads (8 A + 14 B) | stage A(t+1) both halves | barrier |
//        setprio(1) 32 MFMA (m0-3 x n0-3) setprio(0) | barrier}
//   P1: {stage B(t+2) both halves | counted vmcnt(4) | barrier |
//        setprio(1) 24 MFMA (m0-3 x n4-6) setprio(0) | barrier}
// vmcnt queue at P1 wait: [A(t+1) x4, B(t+2) x4] -> vmcnt(4) drains A(t+1),
// leaves B(t+2) in flight (in-order retire). Never drained to 0 in steady state.
// Hazard: bv[4..6] read at P0, >=1 phase before STAGE_B(t+2,cur) writes land.
// Waves 4M x 2N: per-wave 64x112. N exact: 14 tiles x 224 = 3136 (B rows 224+ dead).
// LDS row = 128 B (64 bf16 k). XOR swizzle: granule g of row r stored at g^(r&7).
__global__ __launch_bounds__(512, 2) void conv_mfma(
    const __bf16* __restrict__ Asyn, const __bf16* __restrict__ Xpad,
    const float* __restrict__ bias, float* __restrict__ Out) {
    const int i = blockIdx.x;
    const int xcd = i & 7, slot = i >> 3;        // slot 0..55
    const int bg = slot / 14, ntile = slot - bg * 14;
    const int b = xcd + 8 * bg;                  // all 14 tiles of a sample on one XCD

    __shared__ __bf16 Al[2][256 * 64];           // 2 x 32 KB
    __shared__ __bf16 Bl[2][256 * 64];           // 2 x 32 KB

    const int tid = threadIdx.x;
    const int wid = tid >> 6, lane = tid & 63;   // 8 waves

    // ---- staging map (block-wide per half-tile: 128 rows, 2 async16/thread).
    //      lane -> row lane>>3, physical granule lane&7, logical q = (lane&7)^(lane>>3).
    const int rsub = lane >> 3;
    const int q = (lane & 7) ^ rsub;
    const __bf16* aptr[2][2];                    // [half][chunk] rows 128h + wid*16 + c*8 + rsub
    const __bf16* bptr[2][2];
    const __bf16* xb = Xpad + (size_t)b * (HP * WP) * IC;
    #pragma unroll
    for (int h = 0; h < 2; ++h)
        #pragma unroll
        for (int c = 0; c < 2; ++c) {
            const int r = h * 128 + wid * 16 + c * 8 + rsub;
            aptr[h][c] = Asyn + (size_t)(b * OC + r) * KTOT + q * 8;
            int nn = ntile * NTILE + r;          // rows 224..255 staged but never consumed
            if (nn >= HW) nn -= HW;              // tail clamp: valid memory, values discarded
            const int hh = nn / 56, ww = nn - hh * 56;
            bptr[h][c] = xb + (hh * WP + ww) * IC + q * 8;
        }

    // ---- fragment read offsets (bytes). Row r granule g at r*128 + (g^(r&7))*16.
    //      Linear in frag index since the XOR involves only fr&7. k-half tt -> byte ^64.
    const int wm = wid >> 1;                     // M quarter (0..3), 64 rows
    const int wn = wid & 1;                      // N half (0..1), 112 cols
    const int fr = lane & 15, fq = lane >> 4;
    const int swz = (fq ^ (fr & 7)) * 16;
    const int abase = (wm * 64 + fr) * 128 + swz;    // + mi*2048 (mi 0..3)
    const int bbase = (wn * 112 + fr) * 128 + swz;   // + ni*2048 (ni 0..6)

    f32x4 acc[4][7] = {};

    auto STAGE_A = [&](int t, int cur, int h) {  // tile t's A-half h -> buf cur
        char* base = (char*)&Al[cur][0] + (h * 128 + wid * 16) * 128;
        const int ko = t * 64;                   // Asyn K is linear: t*64
        async16(aptr[h][0] + ko, base);
        async16(aptr[h][1] + ko, base + 1024);
    };
    auto STAGE_B = [&](int t, int cur, int h) {
        const int tap = t >> 2, sub = t & 3;
        const int kh = tap / 3, kw = tap - kh * 3;
        const int ko = (kh * WP + kw) * IC + sub * 64;
        char* base = (char*)&Bl[cur][0] + (h * 128 + wid * 16) * 128;
        async16(bptr[h][0] + ko, base);
        async16(bptr[h][1] + ko, base + 1024);
    };

    auto TILE = [&](int t, int cur) {
        const char* Ab = (const char*)&Al[cur][0];
        const char* Bb = (const char*)&Bl[cur][0];
        bf16x8 af[4][2], bv[7][2];
        // ---- P0: all frag reads (A + B-low first: first MFMA needs af[0],bv[0])
        #pragma unroll
        for (int mi = 0; mi < 4; ++mi)
            #pragma unroll
            for (int tt = 0; tt < 2; ++tt)
                af[mi][tt] = *(const bf16x8*)(Ab + ((abase + mi * 2048) ^ (tt * 64)));
        #pragma unroll
        for (int ni = 0; ni < 7; ++ni)
            #pragma unroll
            for (int tt = 0; tt < 2; ++tt)
                bv[ni][tt] = *(const bf16x8*)(Bb + ((bbase + ni * 2048) ^ (tt * 64)));
        if (t + 1 < NT) { STAGE_A(t + 1, cur ^ 1, 0); STAGE_A(t + 1, cur ^ 1, 1); }
        __builtin_amdgcn_s_barrier();
        __builtin_amdgcn_s_setprio(1);
        #pragma unroll
        for (int tt = 0; tt < 2; ++tt)           // tt outer: dep chains 16 apart
            #pragma unroll
            for (int mi = 0; mi < 4; ++mi)
                #pragma unroll
                for (int ni = 0; ni < 4; ++ni)
                    acc[mi][ni] = __builtin_amdgcn_mfma_f32_16x16x32_bf16(
                        af[mi][tt], bv[ni][tt], acc[mi][ni], 0, 0, 0);
        __builtin_amdgcn_s_setprio(0);
        __builtin_amdgcn_s_barrier();
        // ---- P1: stage B(t+2) into cur (bv regs already hold tile t's B)
        if (t + 2 < NT) { STAGE_B(t + 2, cur, 0); STAGE_B(t + 2, cur, 1); }
        if (t < NT - 2) asm volatile("s_waitcnt vmcnt(4)" ::: "memory");
        else            asm volatile("s_waitcnt vmcnt(0)" ::: "memory");
        __builtin_amdgcn_s_barrier();
        __builtin_amdgcn_s_setprio(1);
        #pragma unroll
        for (int tt = 0; tt < 2; ++tt)           // dep chains 12 apart
            #pragma unroll
            for (int mi = 0; mi < 4; ++mi)
                #pragma unroll
                for (int ni = 4; ni < 7; ++ni)
                    acc[mi][ni] = __builtin_amdgcn_mfma_f32_16x16x32_bf16(
                        af[mi][tt], bv[ni][tt], acc[mi][ni], 0, 0, 0);
        __builtin_amdgcn_s_setprio(0);
        __builtin_amdgcn_s_barrier();
    };

    // prologue: A(0), B(0), B(1); allow B(1) to stay in flight
    STAGE_A(0, 0, 0); STAGE_A(0, 0, 1);
    STAGE_B(0, 0, 0); STAGE_B(0, 0, 1);
    STAGE_B(1, 1, 0); STAGE_B(1, 1, 1);
    asm volatile("s_waitcnt vmcnt(4)" ::: "memory");
    __builtin_amdgcn_s_barrier();

    #pragma unroll 1
    for (int t2 = 0; t2 < NT; t2 += 2) {
        TILE(t2, 0);
        TILE(t2 + 1, 1);
    }

    // ---- store: D row = fq*4 + reg, col = fr. Exact cover -> no col guard ----
    #pragma unroll
    for (int mi = 0; mi < 4; ++mi) {
        #pragma unroll
        for (int r = 0; r < 4; ++r) {
            const int row = wm * 64 + mi * 16 + fq * 4 + r;
            const float bvv = bias[row];
            float* orow = Out + (size_t)(b * OC + row) * HW;
            #pragma unroll
            for (int ni = 0; ni < 7; ++ni) {
                const int col = ntile * NTILE + wn * 112 + ni * 16 + fr;
                orow[col] = acc[mi][ni][r] + bvv;
            }
        }
    }
}

extern "C" void kernel_launch(void* const* d_in, const int* in_sizes, int n_in,
                              void* d_out, int out_size, void* d_ws, size_t ws_size,
                              hipStream_t stream) {
    const float* X    = (const float*)d_in[0];   // [32,256,56,56]
    const float* se   = (const float*)d_in[1];   // [32,64]
    const float* Wt   = (const float*)d_in[2];   // [589824,64]
    const float* bias = (const float*)d_in[3];   // [256]
    __bf16* Xpad = (__bf16*)d_ws;                           // 57.0 MB
    __bf16* Asyn = (__bf16*)((char*)d_ws + XPAD_BYTES);     // 37.75 MB
    float*  Out  = (float*)d_out;

    zero_border<<<1376, 256, 0, stream>>>(Xpad);
    transpose_pad<<<dim3(49, 4, 32), 256, 0, stream>>>(X, Xpad);
    synth<<<2304, 256, 0, stream>>>(se, Wt, Asyn);
    conv_mfma<<<448, 512, 0, stream>>>(Asyn, Xpad, bias, Out);
}